// Round 6
// baseline (41.865 us; speedup 1.0000x reference)
//
#include <hip/hip_runtime.h>
#include <hip/hip_bf16.h>

typedef __attribute__((ext_vector_type(8))) short short8;
typedef __attribute__((ext_vector_type(4))) short short4b;
typedef __attribute__((ext_vector_type(4))) float f32x4;

#define NBATCH 32
#define NT 512
#define NS 512
#define ND 1024
#define BM 128
#define BN 128
#define BK 32                /* elems per K-step */
#define NK (ND / BK)         /* 32 K-steps */

__device__ __forceinline__ short f2bf(float f) {
    union { __hip_bfloat16 h; short s; } u;
    u.h = __float2bfloat16(f);
    return u.s;
}

__device__ __forceinline__ short4b cvt4(float4 a) {
    short4b r;
    r[0] = f2bf(a.x); r[1] = f2bf(a.y); r[2] = f2bf(a.z); r[3] = f2bf(a.w);
    return r;
}

__device__ __forceinline__ float ssq4(float s, float4 a) {
    return fmaf(a.x, a.x, fmaf(a.y, a.y, fmaf(a.z, a.z, fmaf(a.w, a.w, s))));
}

// 128x128 tile, 256 threads = 4 waves (2x2), each wave computes a 64x64
// sub-tile via 4x4 frags of v_mfma_f32_16x16x32_bf16 (BK=32 = one MFMA
// k-depth). Raising the per-wave tile 64x32 -> 64x64 lifts arithmetic
// intensity 21 -> 32 FLOP per LDS byte (LDS read traffic was the tallest
// pole in r5's accounting) while KEEPING 2 blocks/CU (8 waves/CU) for
// cross-block overlap of the phase fences: launch_bounds(256,2) allows the
// ~185 VGPR this needs (acc 64 + two prefetch sets 64 + frags 32 + misc).
// Everything else is r5's proven structure: bf16 converted once at staging,
// depth-2 even/odd reg-set pipeline (vmcnt waits are counted - a set's loads
// are issued 2 full phases before their wait), raw s_barrier + lgkmcnt(0)
// fences (no vmcnt drain in the loop), swizzle u' = (u + (row>>1)) & 3 on
// both ds_write and ds_read sides (measured 0 conflicts), row sum-of-squares
// fused into staging (norms free), XCD-chunked 1D grid (512 % 8 == 0).
__global__ __launch_bounds__(256, 2)
void paircos_mfma(const float* __restrict__ sup, const float* __restrict__ tgt,
                  float* __restrict__ out) {
    __shared__ __align__(16) short As[2][BM * BK]; // targets tiles (8KB each)
    __shared__ __align__(16) short Bs[2][BN * BK]; // supports tiles
    __shared__ float tn[BM];
    __shared__ float sn[BN];

    const int tid = threadIdx.x;
    // XCD-chunked bijective swizzle (512 blocks)
    const int l    = blockIdx.x;
    const int wgid = (l & 7) * 64 + (l >> 3);
    const int b    = wgid >> 4;
    const int til  = wgid & 15;
    const int bt0  = (til >> 2) * BM;
    const int bs0  = (til & 3) * BN;

    // staging: thread owns float4-col c8 (0..7) of rows r0+{0,32,64,96}
    const int c8 = tid & 7;
    const int r0 = tid >> 3; // 0..31

    const float* gA = tgt + (size_t)b * NT * ND + (size_t)(bt0 + r0) * ND + c8 * 4;
    const float* gB = sup + (size_t)b * NS * ND + (size_t)(bs0 + r0) * ND + c8 * 4;

    const int wave = tid >> 6;         // 0..3
    const int lane = tid & 63;
    const int wr  = (wave >> 1) * 64;  // 0 or 64
    const int wc  = (wave & 1) * 64;   // 0 or 64
    const int lhi = lane >> 4;         // 0..3 (k-group of 8)
    const int llo = lane & 15;

    f32x4 acc[4][4];
#pragma unroll
    for (int m = 0; m < 4; ++m)
#pragma unroll
        for (int n = 0; n < 4; ++n)
            acc[m][n] = (f32x4){0.f, 0.f, 0.f, 0.f};

    float sqa[4] = {0.f, 0.f, 0.f, 0.f};
    float sqb[4] = {0.f, 0.f, 0.f, 0.f};

    // two prefetch register sets; all indexing compile-time (rule #20)
    float4 eA[4], eB[4], oA[4], oB[4];

    // LDS staging offset (shorts) for row r0 + j*32: rows differ by multiples
    // of 32 so (row>>1) & 3 is j-invariant -> one u0 for all four.
    const int u0   = ((c8 >> 1) + (r0 >> 1)) & 3;
    const int off0 = r0 * BK + u0 * 8 + (c8 & 1) * 4;

#define LOADT(RA, RB, KK)                                                      \
    do {                                                                       \
        _Pragma("unroll") for (int j = 0; j < 4; ++j) {                        \
            RA[j] = *reinterpret_cast<const float4*>(gA + (KK) * BK + (size_t)j * 32 * ND); \
            RB[j] = *reinterpret_cast<const float4*>(gB + (KK) * BK + (size_t)j * 32 * ND); \
        }                                                                      \
    } while (0)

#define STORET(RA, RB, P)                                                      \
    do {                                                                       \
        _Pragma("unroll") for (int j = 0; j < 4; ++j) {                        \
            sqa[j] = ssq4(sqa[j], RA[j]);                                      \
            *reinterpret_cast<short4b*>(&As[P][off0 + j * 32 * BK]) = cvt4(RA[j]); \
            sqb[j] = ssq4(sqb[j], RB[j]);                                      \
            *reinterpret_cast<short4b*>(&Bs[P][off0 + j * 32 * BK]) = cvt4(RB[j]); \
        }                                                                      \
    } while (0)

#define COMPUTE(P)                                                             \
    do {                                                                       \
        short8 af[4], bfr[4];                                                  \
        _Pragma("unroll") for (int m = 0; m < 4; ++m) {                        \
            const int row = wr + m * 16 + llo;                                 \
            const int off = row * BK + (((lhi + (row >> 1)) & 3) * 8);         \
            af[m] = *reinterpret_cast<const short8*>(&As[P][off]);             \
        }                                                                      \
        _Pragma("unroll") for (int n = 0; n < 4; ++n) {                        \
            const int row = wc + n * 16 + llo;                                 \
            const int off = row * BK + (((lhi + (row >> 1)) & 3) * 8);         \
            bfr[n] = *reinterpret_cast<const short8*>(&Bs[P][off]);            \
        }                                                                      \
        _Pragma("unroll") for (int m = 0; m < 4; ++m)                          \
            _Pragma("unroll") for (int n = 0; n < 4; ++n)                      \
                acc[m][n] = __builtin_amdgcn_mfma_f32_16x16x32_bf16(           \
                    af[m], bfr[n], acc[m][n], 0, 0, 0);                        \
    } while (0)

    // fence: wave's ds ops done, then barrier. No vmcnt drain - the global
    // loads backing the reg sets stay in flight across phases.
#define PHASE_FENCE()                                                          \
    do {                                                                       \
        asm volatile("s_waitcnt lgkmcnt(0)" ::: "memory");                     \
        __builtin_amdgcn_s_barrier();                                          \
        asm volatile("" ::: "memory");                                         \
    } while (0)

    // prologue: tile0 -> buf0; e <- tile1, o <- tile2
    LOADT(eA, eB, 0);
    STORET(eA, eB, 0);
    LOADT(eA, eB, 1);
    LOADT(oA, oB, 2);
    PHASE_FENCE();

    for (int k = 0; k < NK; k += 2) {
        // even phase: MFMA on buf0 (tile k); e holds tile k+1 -> buf1
        STORET(eA, eB, 1);                       // waits only e-loads (k-2 issue)
        if (k + 3 < NK) LOADT(eA, eB, k + 3);
        COMPUTE(0);
        PHASE_FENCE();
        // odd phase: MFMA on buf1 (tile k+1); o holds tile k+2 -> buf0
        if (k + 2 < NK) STORET(oA, oB, 0);
        if (k + 4 < NK) LOADT(oA, oB, k + 4);
        COMPUTE(1);
        PHASE_FENCE();
    }

    // norms: reduce each row's sumsq over the 8 c8-threads (xor 1,2,4 stays
    // within the 8-thread group sharing tid>>3)
#pragma unroll
    for (int d = 1; d < 8; d <<= 1) {
#pragma unroll
        for (int j = 0; j < 4; ++j) {
            sqa[j] += __shfl_xor(sqa[j], d);
            sqb[j] += __shfl_xor(sqb[j], d);
        }
    }
    if (c8 == 0) {
#pragma unroll
        for (int j = 0; j < 4; ++j) {
            tn[r0 + j * 32] = sqrtf(sqa[j]);
            sn[r0 + j * 32] = sqrtf(sqb[j]);
        }
    }
    __syncthreads();

    float* outp = out + (size_t)b * NT * NS;
#pragma unroll
    for (int m = 0; m < 4; ++m) {
        const int lr0 = wr + m * 16 + lhi * 4;
#pragma unroll
        for (int n = 0; n < 4; ++n) {
            const int lc = wc + n * 16 + llo;
            const float snv = sn[lc];
            const int col = bs0 + lc;
#pragma unroll
            for (int j = 0; j < 4; ++j) {
                const float denom = fmaxf(tn[lr0 + j] * snv, 1e-10f);
                outp[(size_t)(bt0 + lr0 + j) * NS + col] =
                    acc[m][n][j] / denom * 0.5f + 0.5f;
            }
        }
    }
}

extern "C" void kernel_launch(void* const* d_in, const int* in_sizes, int n_in,
                              void* d_out, int out_size, void* d_ws, size_t ws_size,
                              hipStream_t stream) {
    const float* sup = (const float*)d_in[0]; // supports [32,512,1024]
    const float* tgt = (const float*)d_in[1]; // targets  [32,512,1024]
    float* out = (float*)d_out;               // [32,512,512] f32
    (void)in_sizes; (void)n_in; (void)out_size; (void)d_ws; (void)ws_size;
    paircos_mfma<<<dim3(16 * NBATCH), 256, 0, stream>>>(sup, tgt, out);
}

// Round 7
// 39.297 us; speedup vs baseline: 1.0653x; 1.0653x over previous
//
#include <hip/hip_runtime.h>
#include <hip/hip_bf16.h>

typedef __attribute__((ext_vector_type(8))) short short8;
typedef __attribute__((ext_vector_type(4))) float f32x4;

#define NBATCH 32
#define NT 512
#define NS 512
#define ND 1024
#define BM 128
#define BN 128
#define BK 32                /* elems per K-step */
#define NK (ND / BK)         /* 32 K-steps */

__device__ __forceinline__ short f2bf(float f) {
    union { __hip_bfloat16 h; short s; } u;
    u.h = __float2bfloat16(f);
    return u.s;
}

__device__ __forceinline__ short8 cvt8(float4 a, float4 b) {
    short8 r;
    r[0] = f2bf(a.x); r[1] = f2bf(a.y); r[2] = f2bf(a.z); r[3] = f2bf(a.w);
    r[4] = f2bf(b.x); r[5] = f2bf(b.y); r[6] = f2bf(b.z); r[7] = f2bf(b.w);
    return r;
}

__device__ __forceinline__ float ssq4(float s, float4 a) {
    return fmaf(a.x, a.x, fmaf(a.y, a.y, fmaf(a.z, a.z, fmaf(a.w, a.w, s))));
}

// r5 geometry (best so far: 39.7us): 128x128 tile, 512 threads = 8 waves
// (2x4), wave = 64x32 out via 4x2 frags of v_mfma_f32_16x16x32_bf16, BK=32,
// 2 blocks/CU = 16 waves/CU. Counter-validated model: LDS port ~1536cy/step
// at 50% duty is the wall (predicted VALUBusy 22% vs measured 24.6, MfmaUtil
// 10 vs 10.2). Round-7 changes attack the phase critical path at fixed
// geometry:
//  1) staging remap: thread owns one contiguous 8-elem segment per operand
//     -> 2 ds_write_b128 (uniform 8-accesses/bank, conflict-optimal) instead
//     of 4 ds_write_b64; prefetch sets halve to 16 VGPR each.
//  2) phase reorder: the 6 MFMA-feeding ds_read_b128 issue BEFORE the
//     cvt+ds_write staging, so the compiler waits only a counted lgkmcnt
//     before the first MFMA and staging runs in the MFMA shadow.
//  3) s_setprio(1) around the MFMA cluster (two phase-offset blocks/CU give
//     the scheduler role diversity to arbitrate).
// Unchanged, proven: bf16 converted once at staging; depth-2 even/odd
// reg-set pipeline (a set's global loads issue 2 full phases before their
// vmcnt wait); raw s_barrier + lgkmcnt(0)-only fences (global loads never
// drained in-loop); swizzle u' = (u + (row>>1)) & 3 on write and read sides
// (measured 0 conflicts); row sum-of-squares fused into staging (norms
// free); XCD-chunked 1D grid (512 % 8 == 0).
__global__ __launch_bounds__(512, 4)
void paircos_mfma(const float* __restrict__ sup, const float* __restrict__ tgt,
                  float* __restrict__ out) {
    __shared__ __align__(16) short As[2][BM * BK]; // targets tiles (8KB each)
    __shared__ __align__(16) short Bs[2][BN * BK]; // supports tiles
    __shared__ float tn[BM];
    __shared__ float sn[BN];

    const int tid = threadIdx.x;
    // XCD-chunked bijective swizzle (512 blocks)
    const int l    = blockIdx.x;
    const int wgid = (l & 7) * 64 + (l >> 3);
    const int b    = wgid >> 4;
    const int til  = wgid & 15;
    const int bt0  = (til >> 2) * BM;
    const int bs0  = (til & 3) * BN;

    // staging: thread owns the 8-elem segment seg (0..3) of row srow (0..127)
    // for both A and B
    const int seg  = tid & 3;
    const int srow = tid >> 2; // 0..127

    const float* gA = tgt + (size_t)b * NT * ND + (size_t)(bt0 + srow) * ND + seg * 8;
    const float* gB = sup + (size_t)b * NS * ND + (size_t)(bs0 + srow) * ND + seg * 8;

    const int wave = tid >> 6;
    const int lane = tid & 63;
    const int wr  = (wave >> 2) * 64;  // 0 or 64
    const int wc  = (wave & 3) * 32;   // 0,32,64,96
    const int lhi = lane >> 4;         // 0..3 (k-group of 8)
    const int llo = lane & 15;

    f32x4 acc[4][2];
#pragma unroll
    for (int m = 0; m < 4; ++m)
#pragma unroll
        for (int n = 0; n < 2; ++n)
            acc[m][n] = (f32x4){0.f, 0.f, 0.f, 0.f};

    float sqa = 0.f, sqb = 0.f;

    // two prefetch register sets, static names (rule #20); 16 VGPR each
    float4 eA0, eA1, eB0, eB1, oA0, oA1, oB0, oB1;

    // LDS staging offset (shorts): row*32 + u'*8, u' = (seg + (srow>>1)) & 3
    const int offw = srow * BK + (((seg + (srow >> 1)) & 3) * 8);

#define LOADT(A0, A1, B0, B1, KK)                                              \
    do {                                                                       \
        A0 = *reinterpret_cast<const float4*>(gA + (KK) * BK);                 \
        A1 = *reinterpret_cast<const float4*>(gA + (KK) * BK + 4);             \
        B0 = *reinterpret_cast<const float4*>(gB + (KK) * BK);                 \
        B1 = *reinterpret_cast<const float4*>(gB + (KK) * BK + 4);             \
    } while (0)

#define STORET(A0, A1, B0, B1, P)                                              \
    do {                                                                       \
        sqa = ssq4(ssq4(sqa, A0), A1);                                         \
        *reinterpret_cast<short8*>(&As[P][offw]) = cvt8(A0, A1);               \
        sqb = ssq4(ssq4(sqb, B0), B1);                                         \
        *reinterpret_cast<short8*>(&Bs[P][offw]) = cvt8(B0, B1);               \
    } while (0)

#define FRAG_READ(P)                                                           \
    do {                                                                       \
        _Pragma("unroll") for (int m = 0; m < 4; ++m) {                        \
            const int row = wr + m * 16 + llo;                                 \
            const int off = row * BK + (((lhi + (row >> 1)) & 3) * 8);         \
            af[m] = *reinterpret_cast<const short8*>(&As[P][off]);             \
        }                                                                      \
        _Pragma("unroll") for (int n = 0; n < 2; ++n) {                        \
            const int row = wc + n * 16 + llo;                                 \
            const int off = row * BK + (((lhi + (row >> 1)) & 3) * 8);         \
            bfr[n] = *reinterpret_cast<const short8*>(&Bs[P][off]);            \
        }                                                                      \
    } while (0)

#define MFMA_BLOCK()                                                           \
    do {                                                                       \
        __builtin_amdgcn_s_setprio(1);                                         \
        _Pragma("unroll") for (int m = 0; m < 4; ++m)                          \
            _Pragma("unroll") for (int n = 0; n < 2; ++n)                      \
                acc[m][n] = __builtin_amdgcn_mfma_f32_16x16x32_bf16(           \
                    af[m], bfr[n], acc[m][n], 0, 0, 0);                        \
        __builtin_amdgcn_s_setprio(0);                                         \
    } while (0)

    // fence: wave's ds ops done, then barrier. No vmcnt drain - the global
    // loads backing the reg sets stay in flight across phases.
#define PHASE_FENCE()                                                          \
    do {                                                                       \
        asm volatile("s_waitcnt lgkmcnt(0)" ::: "memory");                     \
        __builtin_amdgcn_s_barrier();                                          \
        asm volatile("" ::: "memory");                                         \
    } while (0)

    // prologue: tile0 -> buf0; e <- tile1, o <- tile2
    LOADT(eA0, eA1, eB0, eB1, 0);
    STORET(eA0, eA1, eB0, eB1, 0);
    LOADT(eA0, eA1, eB0, eB1, 1);
    LOADT(oA0, oA1, oB0, oB1, 2);
    PHASE_FENCE();

    for (int k = 0; k < NK; k += 2) {
        {
            // even phase: MFMA on buf0 (tile k); e holds tile k+1 -> buf1
            short8 af[4], bfr[2];
            FRAG_READ(0);                        // MFMA-feeding reads first
            STORET(eA0, eA1, eB0, eB1, 1);       // cvt+writes in MFMA shadow
            if (k + 3 < NK) LOADT(eA0, eA1, eB0, eB1, k + 3);
            MFMA_BLOCK();
            PHASE_FENCE();
        }
        {
            // odd phase: MFMA on buf1 (tile k+1); o holds tile k+2 -> buf0
            short8 af[4], bfr[2];
            FRAG_READ(1);
            if (k + 2 < NK) STORET(oA0, oA1, oB0, oB1, 0);
            if (k + 4 < NK) LOADT(oA0, oA1, oB0, oB1, k + 4);
            MFMA_BLOCK();
            PHASE_FENCE();
        }
    }

    // norms: each row's sumsq lives in its 4 seg-threads (consecutive lanes);
    // xor 1,2 reduce within the 4-lane group
    sqa += __shfl_xor(sqa, 1);
    sqa += __shfl_xor(sqa, 2);
    sqb += __shfl_xor(sqb, 1);
    sqb += __shfl_xor(sqb, 2);
    if (seg == 0) {
        tn[srow] = sqrtf(sqa);
        sn[srow] = sqrtf(sqb);
    }
    __syncthreads();

    float* outp = out + (size_t)b * NT * NS;
#pragma unroll
    for (int m = 0; m < 4; ++m) {
        const int lr0 = wr + m * 16 + lhi * 4;
#pragma unroll
        for (int n = 0; n < 2; ++n) {
            const int lc = wc + n * 16 + llo;
            const float snv = sn[lc];
            const int col = bs0 + lc;
#pragma unroll
            for (int j = 0; j < 4; ++j) {
                const float denom = fmaxf(tn[lr0 + j] * snv, 1e-10f);
                outp[(size_t)(bt0 + lr0 + j) * NS + col] =
                    acc[m][n][j] / denom * 0.5f + 0.5f;
            }
        }
    }
}

extern "C" void kernel_launch(void* const* d_in, const int* in_sizes, int n_in,
                              void* d_out, int out_size, void* d_ws, size_t ws_size,
                              hipStream_t stream) {
    const float* sup = (const float*)d_in[0]; // supports [32,512,1024]
    const float* tgt = (const float*)d_in[1]; // targets  [32,512,1024]
    float* out = (float*)d_out;               // [32,512,512] f32
    (void)in_sizes; (void)n_in; (void)out_size; (void)d_ws; (void)ws_size;
    paircos_mfma<<<dim3(16 * NBATCH), 512, 0, stream>>>(sup, tgt, out);
}